// Round 15
// baseline (180.794 us; speedup 1.0000x reference)
//
#include <hip/hip_runtime.h>
#include <math.h>

#define D_MODEL 1024
#define NHEADS 16
#define DK 64
#define SEQ 2048
#define BATCH 2
#define MROWS (BATCH * SEQ)            // 4096

typedef __attribute__((ext_vector_type(8))) short bfrag8;   // 8 bf16 (4 VGPRs)
typedef __attribute__((ext_vector_type(4))) float f32x4;
typedef unsigned short u16;
typedef __attribute__((ext_vector_type(8))) u16 u16x8;
typedef __attribute__((ext_vector_type(4))) u16 u16x4;

#define GLOBAL_AS(p) ((const __attribute__((address_space(1))) void*)(p))
#define LDS_AS(p)    ((__attribute__((address_space(3))) void*)(p))

#define RAW_BARRIER()  __asm__ volatile("s_barrier" ::: "memory")
#define WAIT_VM8()     __asm__ volatile("s_waitcnt vmcnt(8)" ::: "memory")
#define WAIT_VM4()     __asm__ volatile("s_waitcnt vmcnt(4)" ::: "memory")
#define WAIT_VM0()     __asm__ volatile("s_waitcnt vmcnt(0)" ::: "memory")

__device__ inline u16 f2bf(float f) {
  union { float f; unsigned u; } c; c.f = f;
  unsigned r = c.u + 0x7FFF + ((c.u >> 16) & 1);   // RNE
  return (u16)(r >> 16);
}

// pack trunc-bf16(lo), trunc-bf16(hi) into one u32 with a single v_perm_b32
__device__ inline unsigned pack_bf2(float lo, float hi) {
  return __builtin_amdgcn_perm(__float_as_uint(hi), __float_as_uint(lo), 0x07060302);
}

// ---------------------------------------------------------------------------
// Fused fp32->bf16 conversion (x + 4 weights) AND RoPE cos/sin table build.
// Blocks [0, 8192): convert; blocks [8192, 8704): tab.
// ---------------------------------------------------------------------------
struct CvtPtrs { const float* src[5]; };

__global__ __launch_bounds__(256)
void convert_and_tab(CvtPtrs p, u16* __restrict__ dst,
                     const int* __restrict__ pos, float2* __restrict__ tab) {
  const int bi = blockIdx.x;
  if (bi < 8192) {
    size_t base = ((size_t)bi * 256 + threadIdx.x) * 4;
    const size_t XSZ = (size_t)MROWS * D_MODEL;
    const float* s; size_t off;
    if (base < XSZ) { s = p.src[0]; off = base; }
    else {
      size_t j = base - XSZ;
      s = p.src[1 + (int)(j >> 20)];
      off = j & ((1u << 20) - 1);
    }
    float4 v = *(const float4*)(s + off);
    u16 o[4] = { f2bf(v.x), f2bf(v.y), f2bf(v.z), f2bf(v.w) };
    *(u16x4*)(dst + base) = *(u16x4*)o;
  } else {
    int idx = (bi - 8192) * 256 + threadIdx.x;   // 131072 total
    int i = idx & 31, bs = idx >> 5;
    float pp = (float)pos[bs];
    float freq = expf(-(float)i * 0.2878231366242558f);  // ln(10000)/32
    float sn, cs;
    sincosf(pp * freq, &sn, &cs);
    tab[idx] = make_float2(cs, sn);
  }
}

// ---------------------------------------------------------------------------
// Shared bf16 MFMA NT-GEMM core, R17 (proven): 128x128 tile, BK=32, TRIPLE-
// buffered LDS, prefetch distance 2, counted vmcnt(8).
// ---------------------------------------------------------------------------
__device__ inline void gemm_core(const u16* __restrict__ A, const u16* __restrict__ B,
                                 int m0, int n0, u16* As, u16* Bs,
                                 f32x4 acc[4][4]) {
  const int tid = threadIdx.x;
  const int w = tid >> 6, lane = tid & 63;
  const int l15 = lane & 15, quad = lane >> 4;
  const int wm = w >> 1, wn = w & 1;
  const int srow = tid >> 2;
  const int scol = (tid & 3) * 8;

  #pragma unroll
  for (int mi = 0; mi < 4; ++mi)
    #pragma unroll
    for (int ni = 0; ni < 4; ++ni) acc[mi][ni] = (f32x4)0.f;

  #define GSTAGE(T, BUF) do {                                                        \
    _Pragma("unroll")                                                                \
    for (int i_ = 0; i_ < 2; ++i_) {                                                 \
      const u16* ga_ = A + (size_t)((i_ * 64 + srow) + m0) * D_MODEL + (T) * 32 + scol; \
      const u16* gb_ = B + (size_t)((i_ * 64 + srow) + n0) * D_MODEL + (T) * 32 + scol; \
      __builtin_amdgcn_global_load_lds(GLOBAL_AS(ga_),                               \
          LDS_AS(&As[(BUF) * 4096 + (i_ * 64 + w * 16) * 32]), 16, 0, 0);            \
      __builtin_amdgcn_global_load_lds(GLOBAL_AS(gb_),                               \
          LDS_AS(&Bs[(BUF) * 4096 + (i_ * 64 + w * 16) * 32]), 16, 0, 0);            \
    }                                                                                \
  } while (0)

  const int NT = D_MODEL / 32;           // 32 K-steps
  GSTAGE(0, 0);
  GSTAGE(1, 1);
  int sbuf = 2;                          // buffer for tile t+2
  int cbuf = 0;                          // buffer for tile t
  for (int t = 0; t < NT; ++t) {
    RAW_BARRIER();                       // all waves done reading sbuf (tile t-1)
    if (t + 2 < NT) {
      GSTAGE(t + 2, sbuf);
      WAIT_VM8();                        // t's 4 loads done; t+1,t+2's 8 in flight
    } else if (t + 1 < NT) {
      WAIT_VM4();
    } else {
      WAIT_VM0();
    }
    RAW_BARRIER();                       // cbuf fully staged for all waves

    bfrag8 af[4], bfr[4];
    #pragma unroll
    for (int i = 0; i < 4; ++i) {
      af[i]  = *(const bfrag8*)&As[cbuf * 4096 + (wm * 64 + i * 16 + l15) * 32 + quad * 8];
      bfr[i] = *(const bfrag8*)&Bs[cbuf * 4096 + (wn * 64 + i * 16 + l15) * 32 + quad * 8];
    }
    #pragma unroll
    for (int mi = 0; mi < 4; ++mi)
      #pragma unroll
      for (int ni = 0; ni < 4; ++ni)
        acc[mi][ni] = __builtin_amdgcn_mfma_f32_16x16x32_bf16(af[mi], bfr[ni], acc[mi][ni], 0, 0, 0);

    sbuf = cbuf;
    cbuf = (cbuf == 2) ? 0 : cbuf + 1;
  }
  #undef GSTAGE
}

// ---------------------------------------------------------------------------
// Fused QKV GEMM (R17, unchanged).
// ---------------------------------------------------------------------------
struct QKVArgs { const u16* A[3]; const u16* B[3]; u16* dst[3]; const float2* tab; };

__global__ __launch_bounds__(256)
void gemm_qkv_fused(QKVArgs p) {
  __shared__ u16 As[3 * 128 * 32];       // 24KB (triple-buffered)
  __shared__ u16 Bs[3 * 128 * 32];       // 24KB
  const int z = blockIdx.z;
  const int bi = blockIdx.x;
  int m0, n0;
  if (z < 2) { m0 = (bi & 7) * 128; n0 = (bi >> 3) * 128; }   // M=1024 dims, N=4096 s
  else       { m0 = (bi >> 3) * 128; n0 = (bi & 7) * 128; }   // M=4096 s, N=1024 dims
  f32x4 acc[4][4];
  gemm_core(p.A[z], p.B[z], m0, n0, As, Bs, acc);

  const int tid = threadIdx.x;
  const int w = tid >> 6, lane = tid & 63;
  const int l15 = lane & 15, quad = lane >> 4;
  const int wm = w >> 1, wn = w & 1;
  u16* dst = p.dst[z];

  if (z < 2) {
    const int head = (m0 + wm * 64) >> 6;
    const float scale = (z == 0) ? 0.125f * 1.4426950408889634f : 1.0f;
    #pragma unroll
    for (int ni = 0; ni < 4; ++ni) {
      int sg = n0 + wn * 64 + ni * 16 + l15;      // 0..4095
      int b = sg >> 11;
      int s = sg & (SEQ - 1);
      size_t ho = ((size_t)(b * NHEADS + head)) * SEQ * DK;
      #pragma unroll
      for (int mi = 0; mi < 4; ++mi) {
        float4 t = *(const float4*)&p.tab[(size_t)sg * 32 + mi * 8 + quad * 2];
        float e0 = acc[mi][ni][0], o0 = acc[mi][ni][1];
        float e1 = acc[mi][ni][2], o1 = acc[mi][ni][3];
        u16x4 ov = { f2bf((e0 * t.x - o0 * t.y) * scale),
                     f2bf((e0 * t.y + o0 * t.x) * scale),
                     f2bf((e1 * t.z - o1 * t.w) * scale),
                     f2bf((e1 * t.w + o1 * t.z) * scale) };
        *(u16x4*)&dst[ho + (size_t)s * DK + mi * 16 + quad * 4] = ov;
      }
    }
  } else {
    const int b = m0 >> 11;
    const int head = (n0 >> 6) + wn;
    const size_t ho = ((size_t)(b * NHEADS + head)) * SEQ * DK;
    const int row_base = m0 + wm * 64;
    #pragma unroll
    for (int mi = 0; mi < 4; ++mi)
      #pragma unroll
      for (int ni = 0; ni < 4; ++ni) {
        int d = ni * 16 + l15;
        int sb = (row_base + mi * 16 + quad * 4) & (SEQ - 1);
        u16 o[4];
        #pragma unroll
        for (int r = 0; r < 4; ++r) o[r] = f2bf(acc[mi][ni][r]);
        *(u16x4*)&dst[ho + (size_t)d * SEQ + sb] = *(u16x4*)o;
      }
  }
}

// ---------------------------------------------------------------------------
// Output projection GEMM: 128x64 tile (512 blocks). R2 single-buffer form.
// ---------------------------------------------------------------------------
__global__ __launch_bounds__(256)
void gemm_out_bf16(const u16* __restrict__ A, const u16* __restrict__ B,
                   float* __restrict__ C) {
  __shared__ u16 As[128 * 32];
  __shared__ u16 Bs[64 * 32];
  const int m0 = blockIdx.y * 128, n0 = blockIdx.x * 64;
  const int tid = threadIdx.x;
  const int w = tid >> 6, lane = tid & 63;
  const int l15 = lane & 15, quad = lane >> 4;
  const int wm = w >> 1, wn = w & 1;
  const int lrow = lane >> 2;
  const int lcol = (lane & 3) * 8;

  f32x4 acc[4][2];
  #pragma unroll
  for (int mi = 0; mi < 4; ++mi)
    #pragma unroll
    for (int ni = 0; ni < 2; ++ni) acc[mi][ni] = (f32x4)0.f;

  for (int k0 = 0; k0 < D_MODEL; k0 += 32) {
    __syncthreads();
    #pragma unroll
    for (int i = 0; i < 2; ++i) {
      int row = (i * 4 + w) * 16 + lrow;
      const u16* ga = A + (size_t)(m0 + row) * D_MODEL + k0 + lcol;
      __builtin_amdgcn_global_load_lds(GLOBAL_AS(ga), LDS_AS(&As[(i * 4 + w) * 16 * 32]), 16, 0, 0);
    }
    {
      int row = w * 16 + lrow;
      const u16* gb = B + (size_t)(n0 + row) * D_MODEL + k0 + lcol;
      __builtin_amdgcn_global_load_lds(GLOBAL_AS(gb), LDS_AS(&Bs[w * 16 * 32]), 16, 0, 0);
    }
    __syncthreads();

    bfrag8 af[4], bfr[2];
    #pragma unroll
    for (int i = 0; i < 4; ++i)
      af[i] = *(const bfrag8*)&As[(wm * 64 + i * 16 + l15) * 32 + quad * 8];
    #pragma unroll
    for (int i = 0; i < 2; ++i)
      bfr[i] = *(const bfrag8*)&Bs[(wn * 32 + i * 16 + l15) * 32 + quad * 8];
    #pragma unroll
    for (int mi = 0; mi < 4; ++mi)
      #pragma unroll
      for (int ni = 0; ni < 2; ++ni)
        acc[mi][ni] = __builtin_amdgcn_mfma_f32_16x16x32_bf16(af[mi], bfr[ni], acc[mi][ni], 0, 0, 0);
  }

  #pragma unroll
  for (int mi = 0; mi < 4; ++mi)
    #pragma unroll
    for (int ni = 0; ni < 2; ++ni)
      #pragma unroll
      for (int r = 0; r < 4; ++r) {
        int row = m0 + wm * 64 + mi * 16 + quad * 4 + r;
        int col = n0 + wn * 32 + ni * 16 + l15;
        C[(size_t)row * D_MODEL + col] = acc[mi][ni][r];
      }
}

// ---------------------------------------------------------------------------
// Flash attention, R24: 4-wave WITHIN-TILE-REUSE blocks. R23's counters show
// DS-throughput-bound (~1280 DS cyc of 1530 cyc/tile-unit; 1 frag read per
// MFMA). Wave (wq,kh) = 32 q-rows (2 ALWAYS-ACTIVE groups of 16) x 32 keys:
// kf0/kf1/vf read ONCE, used for BOTH q-groups -> 16 MFMA / 8 frag reads
// (0.5 reads/MFMA, frag traffic halved). Unlike R20's failed pairing: grid
// stays 1024 (4 independent blocks/CU -- the property that made R19/R23
// work), no inactive phases, same qt balance and fragment algebra.
// Keeps R23's setprio-around-MFMA and no-clamp exp2.
// ---------------------------------------------------------------------------
__global__ __launch_bounds__(256, 4)
void attn_mfma(const u16* __restrict__ Qbf, const u16* __restrict__ Kbf,
               const u16* __restrict__ Vtb, u16* __restrict__ obb) {
  __shared__ u16 Ks[2][64 * 64];
  __shared__ u16 Vt[2][64 * 64];

  const int tid = threadIdx.x;
  const int w = tid >> 6, lane = tid & 63;
  const int l15 = lane & 15, quad = lane >> 4;
  const int wq = w & 1, kh = w >> 1;       // 32 q-rows x 32 keys per wave

  const int bid = blockIdx.x;
  const int hb = bid & 31;                 // XCD = hb % 8 -> head-local L2
  const int g  = bid >> 5;                 // 0..31
  const int tt = (g & 7) | ((g & 16) >> 1);        // 0..15
  const int qt = (g & 8) ? (31 - tt) : tt;         // balanced diagonal pairing
  const int b = hb >> 4, h = hb & 15;
  const size_t ho = (size_t)hb * SEQ * DK;
  const int qrow0 = qt * 64 + wq * 32;     // group qg: rows qrow0 + qg*16 ..

  bfrag8 qf[2][2];
  #pragma unroll
  for (int qg = 0; qg < 2; ++qg)
    #pragma unroll
    for (int hh = 0; hh < 2; ++hh)
      qf[qg][hh] = *(const bfrag8*)&Qbf[ho + (size_t)(qrow0 + qg * 16 + l15) * DK + hh * 32 + quad * 8];

  f32x4 oacc[2][4];
  float l0 = 0.f, l1 = 0.f;
  #pragma unroll
  for (int qg = 0; qg < 2; ++qg)
    #pragma unroll
    for (int n0 = 0; n0 < 4; ++n0) oacc[qg][n0] = (f32x4)0.f;

  // staging: 256 threads, 2 rounds of 32 rows each for K and V.
  const int srow = w * 8 + (lane >> 3);              // 0..31
  const int scc = ((lane & 7) ^ ((lane >> 3) & 7)) * 8;  // XOR-swizzled chunk

  // bpermute source-lane byte addresses: lane = (quad&1)*32 + (j>>1)*16 + l15
  const int adr0 = (((quad & 1) << 5) + l15) << 2;
  const int adr1 = adr0 + 64;

  #define STAGE(T, BUF) do {                                                         \
    int j0_ = (T) * 64;                                                              \
    _Pragma("unroll")                                                                \
    for (int r_ = 0; r_ < 2; ++r_) {                                                 \
      int row_ = r_ * 32 + srow;                                                     \
      __builtin_amdgcn_global_load_lds(GLOBAL_AS(Kbf + ho + (size_t)(j0_ + row_) * DK + scc), \
                                       LDS_AS(&Ks[BUF][(r_ * 32 + w * 8) * 64]), 16, 0, 0);   \
      __builtin_amdgcn_global_load_lds(GLOBAL_AS(Vtb + ho + (size_t)row_ * SEQ + j0_ + scc),  \
                                       LDS_AS(&Vt[BUF][(r_ * 32 + w * 8) * 64]), 16, 0, 0);   \
    }                                                                                \
  } while (0)

  const int ntiles = qt + 1;
  STAGE(0, 0);

  for (int t = 0; t < ntiles; ++t) {
    const int j0 = t * 64;
    const int buf = t & 1;
    RAW_BARRIER();                         // all waves done reading buf^1 (tile t-1)
    if (t + 1 < ntiles) {
      STAGE(t + 1, buf ^ 1);
      WAIT_VM4();                          // tile t's 4 loads complete; t+1's in flight
    } else {
      WAIT_VM0();
    }
    RAW_BARRIER();                         // buf fully staged by all 4 waves

    // ---- S^T = K·Q^T: kf read once, used for BOTH q-groups ----
    f32x4 sc[2][2];
    const int sw = l15 & 7;
    __builtin_amdgcn_s_setprio(1);
    #pragma unroll
    for (int st = 0; st < 2; ++st) {
      int key = kh * 32 + st * 16 + l15;
      bfrag8 kf0 = *(const bfrag8*)&Ks[buf][key * 64 + ((quad ^ sw) * 8)];
      bfrag8 kf1 = *(const bfrag8*)&Ks[buf][key * 64 + (((4 + quad) ^ sw) * 8)];
      #pragma unroll
      for (int qg = 0; qg < 2; ++qg) {
        sc[qg][st] = __builtin_amdgcn_mfma_f32_16x16x32_bf16(kf0, qf[qg][0], (f32x4)0.f, 0, 0, 0);
        sc[qg][st] = __builtin_amdgcn_mfma_f32_16x16x32_bf16(kf1, qf[qg][1], sc[qg][st], 0, 0, 0);
      }
    }
    __builtin_amdgcn_s_setprio(0);

    // ---- causal masks (per-group, wave-uniform conditions) ----
    #pragma unroll
    for (int qg = 0; qg < 2; ++qg) {
      const int qrb = qrow0 + qg * 16;
      if (j0 + 63 > qrb) {
        #pragma unroll
        for (int st = 0; st < 2; ++st)
          #pragma unroll
          for (int r = 0; r < 4; ++r) {
            int key = j0 + kh * 32 + st * 16 + quad * 4 + r;
            if (key > qrb + l15) sc[qg][st][r] = -60.f;
          }
      }
    }

    // ---- fixed-base softmax: p = exp2(s); pack; per-group exchange ----
    bfrag8 pf[2];
    #pragma unroll
    for (int qg = 0; qg < 2; ++qg) {
      unsigned pk[2][2];
      float rs = 0.f;
      #pragma unroll
      for (int st = 0; st < 2; ++st) {
        float p0 = __builtin_amdgcn_exp2f(sc[qg][st][0]);
        float p1 = __builtin_amdgcn_exp2f(sc[qg][st][1]);
        float p2 = __builtin_amdgcn_exp2f(sc[qg][st][2]);
        float p3 = __builtin_amdgcn_exp2f(sc[qg][st][3]);
        rs += (p0 + p1) + (p2 + p3);
        pk[st][0] = pack_bf2(p0, p1);
        pk[st][1] = pack_bf2(p2, p3);
      }
      if (qg == 0) l0 += rs; else l1 += rs;

      union PU { bfrag8 f; int i[4]; } u0;
      #pragma unroll
      for (int j = 0; j < 4; ++j) {
        const int adr = (j & 2) ? adr1 : adr0;
        int lo0 = __builtin_amdgcn_ds_bpermute(adr, (int)pk[0][j & 1]);
        int hi0 = __builtin_amdgcn_ds_bpermute(adr, (int)pk[1][j & 1]);
        u0.i[j] = (quad & 2) ? hi0 : lo0;
      }
      pf[qg] = u0.f;
    }

    // ---- O^T += V^T·P: vf read once, used for BOTH q-groups ----
    __builtin_amdgcn_s_setprio(1);
    #pragma unroll
    for (int n0 = 0; n0 < 4; ++n0) {
      bfrag8 vf = *(const bfrag8*)&Vt[buf][(n0 * 16 + l15) * 64 + (((kh * 4 + quad) ^ sw) * 8)];
      oacc[0][n0] = __builtin_amdgcn_mfma_f32_16x16x32_bf16(vf, pf[0], oacc[0][n0], 0, 0, 0);
      oacc[1][n0] = __builtin_amdgcn_mfma_f32_16x16x32_bf16(vf, pf[1], oacc[1][n0], 0, 0, 0);
    }
    __builtin_amdgcn_s_setprio(0);
  }
  #undef STAGE

  // ---- epilogue: quad-reduce l per group; kh-merge via LDS; store ----
  l0 += __shfl_xor(l0, 16); l0 += __shfl_xor(l0, 32);
  l1 += __shfl_xor(l1, 16); l1 += __shfl_xor(l1, 32);

  RAW_BARRIER();                           // all waves done reading K/V LDS
  float* osc = (float*)Ks;                 // 4 slots x 64 lanes x 16 f = 16KB
  float* lsc = (float*)Vt;                 // 4 x 16 f
  if (kh == 1) {
    #pragma unroll
    for (int qg = 0; qg < 2; ++qg)
      #pragma unroll
      for (int n0 = 0; n0 < 4; ++n0)
        *(f32x4*)&osc[((wq * 2 + qg) * 64 + lane) * 16 + n0 * 4] = oacc[qg][n0];
    if (quad == 0) {
      lsc[(wq * 2 + 0) * 16 + l15] = l0;
      lsc[(wq * 2 + 1) * 16 + l15] = l1;
    }
  }
  RAW_BARRIER();
  if (kh == 0) {
    #pragma unroll
    for (int qg = 0; qg < 2; ++qg) {
      float lt = (qg ? l1 : l0) + lsc[(wq * 2 + qg) * 16 + l15];
      float inv = 1.f / lt;
      int q = qrow0 + qg * 16 + l15;
      #pragma unroll
      for (int n0 = 0; n0 < 4; ++n0) {
        f32x4 o2 = *(const f32x4*)&osc[((wq * 2 + qg) * 64 + lane) * 16 + n0 * 4];
        u16x4 ov = { f2bf((oacc[qg][n0][0] + o2[0]) * inv), f2bf((oacc[qg][n0][1] + o2[1]) * inv),
                     f2bf((oacc[qg][n0][2] + o2[2]) * inv), f2bf((oacc[qg][n0][3] + o2[3]) * inv) };
        *(u16x4*)&obb[(size_t)(b * SEQ + q) * D_MODEL + h * DK + n0 * 16 + quad * 4] = ov;
      }
    }
  }
}

// ---------------------------------------------------------------------------
extern "C" void kernel_launch(void* const* d_in, const int* in_sizes, int n_in,
                              void* d_out, int out_size, void* d_ws, size_t ws_size,
                              hipStream_t stream) {
  const float* x  = (const float*)d_in[0];
  const float* Wq = (const float*)d_in[1];
  const float* Wk = (const float*)d_in[2];
  const float* Wv = (const float*)d_in[3];
  const float* Wo = (const float*)d_in[4];
  const int* pos  = (const int*)d_in[5];

  const size_t XSZ = (size_t)MROWS * D_MODEL;   // 4M elems
  const size_t WSZ = (size_t)D_MODEL * D_MODEL; // 1M elems

  u16* bfb = (u16*)d_ws;
  u16* xb  = bfb;                     // 4M
  u16* wqb = xb  + XSZ;
  u16* wkb = wqb + WSZ;
  u16* wvb = wkb + WSZ;
  u16* wob = wvb + WSZ;
  u16* Qbf = wob + WSZ;               // 4M  [b,h,s,64]
  u16* Kbf = Qbf + XSZ;               // 4M  [b,h,s,64]
  u16* Vtb = Kbf + XSZ;               // 4M  [b,h,64,s]
  u16* obb = Vtb + XSZ;               // 4M  [b*s, h*64]
  float2* tab = (float2*)(obb + XSZ); // 131072 float2

  // 1. convert x + weights to bf16, and build RoPE table (fused)
  CvtPtrs cp; cp.src[0] = x; cp.src[1] = Wq; cp.src[2] = Wk; cp.src[3] = Wv; cp.src[4] = Wo;
  convert_and_tab<<<8192 + 512, 256, 0, stream>>>(cp, xb, pos, tab);

  // 2. QKV projections with fused RoPE/repack/V-transpose epilogue
  QKVArgs qp;
  qp.A[0] = wqb; qp.A[1] = wkb; qp.A[2] = xb;
  qp.B[0] = xb;  qp.B[1] = xb;  qp.B[2] = wvb;
  qp.dst[0] = Qbf; qp.dst[1] = Kbf; qp.dst[2] = Vtb;
  qp.tab = tab;
  gemm_qkv_fused<<<dim3(256, 1, 3), 256, 0, stream>>>(qp);

  // 3. flash attention: 1024 4-wave within-tile-reuse blocks
  attn_mfma<<<dim3(1024), 256, 0, stream>>>(Qbf, Kbf, Vtb, obb);

  // 4. output projection (128x64 tiles, 512 blocks)
  gemm_out_bf16<<<dim3(D_MODEL / 64, MROWS / 128), 256, 0, stream>>>(obb, wob, (float*)d_out);
}

// Round 16
// 180.759 us; speedup vs baseline: 1.0002x; 1.0002x over previous
//
#include <hip/hip_runtime.h>
#include <math.h>

#define D_MODEL 1024
#define NHEADS 16
#define DK 64
#define SEQ 2048
#define BATCH 2
#define MROWS (BATCH * SEQ)            // 4096

typedef __attribute__((ext_vector_type(8))) short bfrag8;   // 8 bf16 (4 VGPRs)
typedef __attribute__((ext_vector_type(4))) float f32x4;
typedef unsigned short u16;
typedef __attribute__((ext_vector_type(8))) u16 u16x8;
typedef __attribute__((ext_vector_type(4))) u16 u16x4;

#define GLOBAL_AS(p) ((const __attribute__((address_space(1))) void*)(p))
#define LDS_AS(p)    ((__attribute__((address_space(3))) void*)(p))

#define RAW_BARRIER()  __asm__ volatile("s_barrier" ::: "memory")
#define WAIT_VM8()     __asm__ volatile("s_waitcnt vmcnt(8)" ::: "memory")
#define WAIT_VM4()     __asm__ volatile("s_waitcnt vmcnt(4)" ::: "memory")
#define WAIT_VM2()     __asm__ volatile("s_waitcnt vmcnt(2)" ::: "memory")
#define WAIT_VM0()     __asm__ volatile("s_waitcnt vmcnt(0)" ::: "memory")

__device__ inline u16 f2bf(float f) {
  union { float f; unsigned u; } c; c.f = f;
  unsigned r = c.u + 0x7FFF + ((c.u >> 16) & 1);   // RNE
  return (u16)(r >> 16);
}

// pack trunc-bf16(lo), trunc-bf16(hi) into one u32 with a single v_perm_b32
__device__ inline unsigned pack_bf2(float lo, float hi) {
  return __builtin_amdgcn_perm(__float_as_uint(hi), __float_as_uint(lo), 0x07060302);
}

// ---------------------------------------------------------------------------
// Fused fp32->bf16 conversion (x + 4 weights) AND RoPE cos/sin table build.
// Blocks [0, 8192): convert; blocks [8192, 8704): tab.
// ---------------------------------------------------------------------------
struct CvtPtrs { const float* src[5]; };

__global__ __launch_bounds__(256)
void convert_and_tab(CvtPtrs p, u16* __restrict__ dst,
                     const int* __restrict__ pos, float2* __restrict__ tab) {
  const int bi = blockIdx.x;
  if (bi < 8192) {
    size_t base = ((size_t)bi * 256 + threadIdx.x) * 4;
    const size_t XSZ = (size_t)MROWS * D_MODEL;
    const float* s; size_t off;
    if (base < XSZ) { s = p.src[0]; off = base; }
    else {
      size_t j = base - XSZ;
      s = p.src[1 + (int)(j >> 20)];
      off = j & ((1u << 20) - 1);
    }
    float4 v = *(const float4*)(s + off);
    u16 o[4] = { f2bf(v.x), f2bf(v.y), f2bf(v.z), f2bf(v.w) };
    *(u16x4*)(dst + base) = *(u16x4*)o;
  } else {
    int idx = (bi - 8192) * 256 + threadIdx.x;   // 131072 total
    int i = idx & 31, bs = idx >> 5;
    float pp = (float)pos[bs];
    float freq = expf(-(float)i * 0.2878231366242558f);  // ln(10000)/32
    float sn, cs;
    sincosf(pp * freq, &sn, &cs);
    tab[idx] = make_float2(cs, sn);
  }
}

// ---------------------------------------------------------------------------
// Shared bf16 MFMA NT-GEMM core, R17 (proven): 128x128 tile, BK=32, TRIPLE-
// buffered LDS, prefetch distance 2, counted vmcnt(8). Covers the ~500-900cyc
// L2/L3-miss latency that depth-1 (R14, null) could not.
// ---------------------------------------------------------------------------
__device__ inline void gemm_core(const u16* __restrict__ A, const u16* __restrict__ B,
                                 int m0, int n0, u16* As, u16* Bs,
                                 f32x4 acc[4][4]) {
  const int tid = threadIdx.x;
  const int w = tid >> 6, lane = tid & 63;
  const int l15 = lane & 15, quad = lane >> 4;
  const int wm = w >> 1, wn = w & 1;
  const int srow = tid >> 2;
  const int scol = (tid & 3) * 8;

  #pragma unroll
  for (int mi = 0; mi < 4; ++mi)
    #pragma unroll
    for (int ni = 0; ni < 4; ++ni) acc[mi][ni] = (f32x4)0.f;

  #define GSTAGE(T, BUF) do {                                                        \
    _Pragma("unroll")                                                                \
    for (int i_ = 0; i_ < 2; ++i_) {                                                 \
      const u16* ga_ = A + (size_t)((i_ * 64 + srow) + m0) * D_MODEL + (T) * 32 + scol; \
      const u16* gb_ = B + (size_t)((i_ * 64 + srow) + n0) * D_MODEL + (T) * 32 + scol; \
      __builtin_amdgcn_global_load_lds(GLOBAL_AS(ga_),                               \
          LDS_AS(&As[(BUF) * 4096 + (i_ * 64 + w * 16) * 32]), 16, 0, 0);            \
      __builtin_amdgcn_global_load_lds(GLOBAL_AS(gb_),                               \
          LDS_AS(&Bs[(BUF) * 4096 + (i_ * 64 + w * 16) * 32]), 16, 0, 0);            \
    }                                                                                \
  } while (0)

  const int NT = D_MODEL / 32;           // 32 K-steps
  GSTAGE(0, 0);
  GSTAGE(1, 1);
  int sbuf = 2;                          // buffer for tile t+2
  int cbuf = 0;                          // buffer for tile t
  for (int t = 0; t < NT; ++t) {
    RAW_BARRIER();                       // all waves done reading sbuf (tile t-1)
    if (t + 2 < NT) {
      GSTAGE(t + 2, sbuf);
      WAIT_VM8();                        // t's 4 loads done; t+1,t+2's 8 in flight
    } else if (t + 1 < NT) {
      WAIT_VM4();
    } else {
      WAIT_VM0();
    }
    RAW_BARRIER();                       // cbuf fully staged for all waves

    bfrag8 af[4], bfr[4];
    #pragma unroll
    for (int i = 0; i < 4; ++i) {
      af[i]  = *(const bfrag8*)&As[cbuf * 4096 + (wm * 64 + i * 16 + l15) * 32 + quad * 8];
      bfr[i] = *(const bfrag8*)&Bs[cbuf * 4096 + (wn * 64 + i * 16 + l15) * 32 + quad * 8];
    }
    #pragma unroll
    for (int mi = 0; mi < 4; ++mi)
      #pragma unroll
      for (int ni = 0; ni < 4; ++ni)
        acc[mi][ni] = __builtin_amdgcn_mfma_f32_16x16x32_bf16(af[mi], bfr[ni], acc[mi][ni], 0, 0, 0);

    sbuf = cbuf;
    cbuf = (cbuf == 2) ? 0 : cbuf + 1;
  }
  #undef GSTAGE
}

// ---------------------------------------------------------------------------
// Fused QKV GEMM (R17, unchanged).
// ---------------------------------------------------------------------------
struct QKVArgs { const u16* A[3]; const u16* B[3]; u16* dst[3]; const float2* tab; };

__global__ __launch_bounds__(256)
void gemm_qkv_fused(QKVArgs p) {
  __shared__ u16 As[3 * 128 * 32];       // 24KB (triple-buffered)
  __shared__ u16 Bs[3 * 128 * 32];       // 24KB
  const int z = blockIdx.z;
  const int bi = blockIdx.x;
  int m0, n0;
  if (z < 2) { m0 = (bi & 7) * 128; n0 = (bi >> 3) * 128; }   // M=1024 dims, N=4096 s
  else       { m0 = (bi >> 3) * 128; n0 = (bi & 7) * 128; }   // M=4096 s, N=1024 dims
  f32x4 acc[4][4];
  gemm_core(p.A[z], p.B[z], m0, n0, As, Bs, acc);

  const int tid = threadIdx.x;
  const int w = tid >> 6, lane = tid & 63;
  const int l15 = lane & 15, quad = lane >> 4;
  const int wm = w >> 1, wn = w & 1;
  u16* dst = p.dst[z];

  if (z < 2) {
    const int head = (m0 + wm * 64) >> 6;
    const float scale = (z == 0) ? 0.125f * 1.4426950408889634f : 1.0f;
    #pragma unroll
    for (int ni = 0; ni < 4; ++ni) {
      int sg = n0 + wn * 64 + ni * 16 + l15;      // 0..4095
      int b = sg >> 11;
      int s = sg & (SEQ - 1);
      size_t ho = ((size_t)(b * NHEADS + head)) * SEQ * DK;
      #pragma unroll
      for (int mi = 0; mi < 4; ++mi) {
        float4 t = *(const float4*)&p.tab[(size_t)sg * 32 + mi * 8 + quad * 2];
        float e0 = acc[mi][ni][0], o0 = acc[mi][ni][1];
        float e1 = acc[mi][ni][2], o1 = acc[mi][ni][3];
        u16x4 ov = { f2bf((e0 * t.x - o0 * t.y) * scale),
                     f2bf((e0 * t.y + o0 * t.x) * scale),
                     f2bf((e1 * t.z - o1 * t.w) * scale),
                     f2bf((e1 * t.w + o1 * t.z) * scale) };
        *(u16x4*)&dst[ho + (size_t)s * DK + mi * 16 + quad * 4] = ov;
      }
    }
  } else {
    const int b = m0 >> 11;
    const int head = (n0 >> 6) + wn;
    const size_t ho = ((size_t)(b * NHEADS + head)) * SEQ * DK;
    const int row_base = m0 + wm * 64;
    #pragma unroll
    for (int mi = 0; mi < 4; ++mi)
      #pragma unroll
      for (int ni = 0; ni < 4; ++ni) {
        int d = ni * 16 + l15;
        int sb = (row_base + mi * 16 + quad * 4) & (SEQ - 1);
        u16 o[4];
        #pragma unroll
        for (int r = 0; r < 4; ++r) o[r] = f2bf(acc[mi][ni][r]);
        *(u16x4*)&dst[ho + (size_t)d * SEQ + sb] = *(u16x4*)o;
      }
  }
}

// ---------------------------------------------------------------------------
// Output projection GEMM: 128x64 tile (512 blocks). R2 single-buffer form
// (proven best; both dbuf variants null-to-negative).
// ---------------------------------------------------------------------------
__global__ __launch_bounds__(256)
void gemm_out_bf16(const u16* __restrict__ A, const u16* __restrict__ B,
                   float* __restrict__ C) {
  __shared__ u16 As[128 * 32];
  __shared__ u16 Bs[64 * 32];
  const int m0 = blockIdx.y * 128, n0 = blockIdx.x * 64;
  const int tid = threadIdx.x;
  const int w = tid >> 6, lane = tid & 63;
  const int l15 = lane & 15, quad = lane >> 4;
  const int wm = w >> 1, wn = w & 1;
  const int lrow = lane >> 2;
  const int lcol = (lane & 3) * 8;

  f32x4 acc[4][2];
  #pragma unroll
  for (int mi = 0; mi < 4; ++mi)
    #pragma unroll
    for (int ni = 0; ni < 2; ++ni) acc[mi][ni] = (f32x4)0.f;

  for (int k0 = 0; k0 < D_MODEL; k0 += 32) {
    __syncthreads();
    #pragma unroll
    for (int i = 0; i < 2; ++i) {
      int row = (i * 4 + w) * 16 + lrow;
      const u16* ga = A + (size_t)(m0 + row) * D_MODEL + k0 + lcol;
      __builtin_amdgcn_global_load_lds(GLOBAL_AS(ga), LDS_AS(&As[(i * 4 + w) * 16 * 32]), 16, 0, 0);
    }
    {
      int row = w * 16 + lrow;
      const u16* gb = B + (size_t)(n0 + row) * D_MODEL + k0 + lcol;
      __builtin_amdgcn_global_load_lds(GLOBAL_AS(gb), LDS_AS(&Bs[w * 16 * 32]), 16, 0, 0);
    }
    __syncthreads();

    bfrag8 af[4], bfr[2];
    #pragma unroll
    for (int i = 0; i < 4; ++i)
      af[i] = *(const bfrag8*)&As[(wm * 64 + i * 16 + l15) * 32 + quad * 8];
    #pragma unroll
    for (int i = 0; i < 2; ++i)
      bfr[i] = *(const bfrag8*)&Bs[(wn * 32 + i * 16 + l15) * 32 + quad * 8];
    #pragma unroll
    for (int mi = 0; mi < 4; ++mi)
      #pragma unroll
      for (int ni = 0; ni < 2; ++ni)
        acc[mi][ni] = __builtin_amdgcn_mfma_f32_16x16x32_bf16(af[mi], bfr[ni], acc[mi][ni], 0, 0, 0);
  }

  #pragma unroll
  for (int mi = 0; mi < 4; ++mi)
    #pragma unroll
    for (int ni = 0; ni < 2; ++ni)
      #pragma unroll
      for (int r = 0; r < 4; ++r) {
        int row = m0 + wm * 64 + mi * 16 + quad * 4 + r;
        int col = n0 + wn * 32 + ni * 16 + l15;
        C[(size_t)row * D_MODEL + col] = acc[mi][ni][r];
      }
}

// ---------------------------------------------------------------------------
// Flash attention, R23 (the 176.9us-best, restored): 1024 8-wave KEY-SPLIT
// blocks (32 waves/CU) + setprio around MFMA clusters + no-clamp exp2.
// Session-final structure. Cross-variant evidence (R13/R18/R19/R20/R21/R24):
// wave-slot residency dominates; 32 waves/CU is the empirical optimum; both
// reuse variants (paired-q, within-tile) lost more residency than they
// saved in DS traffic (SQ_LDS_BANK_CONFLICT is staging/bpermute-dominated,
// invariant under frag-read reuse).
// ---------------------------------------------------------------------------
__global__ __launch_bounds__(512, 8)
void attn_mfma(const u16* __restrict__ Qbf, const u16* __restrict__ Kbf,
               const u16* __restrict__ Vtb, u16* __restrict__ obb) {
  __shared__ u16 Ks[2][64 * 64];
  __shared__ u16 Vt[2][64 * 64];

  const int tid = threadIdx.x;
  const int w = tid >> 6, lane = tid & 63;
  const int l15 = lane & 15, quad = lane >> 4;
  const int wq = w & 3, kh = w >> 2;

  const int bid = blockIdx.x;
  const int hb = bid & 31;                 // XCD = hb % 8 -> head-local L2
  const int g  = bid >> 5;                 // 0..31
  const int tt = (g & 7) | ((g & 16) >> 1);        // 0..15
  const int qt = (g & 8) ? (31 - tt) : tt;         // balanced diagonal pairing
  const int b = hb >> 4, h = hb & 15;
  const size_t ho = (size_t)hb * SEQ * DK;
  const int qrow_base = qt * 64 + wq * 16;

  bfrag8 qf[2];
  #pragma unroll
  for (int hh = 0; hh < 2; ++hh)
    qf[hh] = *(const bfrag8*)&Qbf[ho + (size_t)(qrow_base + l15) * DK + hh * 32 + quad * 8];

  f32x4 oacc[4];
  float l_ = 0.f;
  #pragma unroll
  for (int n0 = 0; n0 < 4; ++n0) oacc[n0] = (f32x4)0.f;

  // staging: 512 threads cover the full 64x64 tile; 1 K + 1 V chunk each.
  const int srow = w * 8 + (lane >> 3);              // 0..63
  const int scc = ((lane & 7) ^ ((lane >> 3) & 7)) * 8;  // XOR-swizzled chunk

  // bpermute source-lane byte addresses: lane = (quad&1)*32 + (j>>1)*16 + l15
  const int adr0 = (((quad & 1) << 5) + l15) << 2;
  const int adr1 = adr0 + 64;

  #define STAGE(T, BUF) do {                                                         \
    int j0_ = (T) * 64;                                                              \
    __builtin_amdgcn_global_load_lds(GLOBAL_AS(Kbf + ho + (size_t)(j0_ + srow) * DK + scc), \
                                     LDS_AS(&Ks[BUF][w * 512]), 16, 0, 0);           \
    __builtin_amdgcn_global_load_lds(GLOBAL_AS(Vtb + ho + (size_t)srow * SEQ + j0_ + scc),  \
                                     LDS_AS(&Vt[BUF][w * 512]), 16, 0, 0);           \
  } while (0)

  const int ntiles = qt + 1;
  STAGE(0, 0);

  for (int t = 0; t < ntiles; ++t) {
    const int j0 = t * 64;
    const int buf = t & 1;
    RAW_BARRIER();                         // all waves done reading buf^1 (tile t-1)
    if (t + 1 < ntiles) {
      STAGE(t + 1, buf ^ 1);
      WAIT_VM2();                          // tile t's 2 loads complete; t+1's in flight
    } else {
      WAIT_VM0();
    }
    RAW_BARRIER();                         // buf fully staged by all 8 waves

    // ---- S^T = K·Q^T (this wave's 32 keys x its 16 q-rows) ----
    f32x4 sc[2];
    const int sw = l15 & 7;
    __builtin_amdgcn_s_setprio(1);
    #pragma unroll
    for (int st = 0; st < 2; ++st) {
      int key = kh * 32 + st * 16 + l15;
      bfrag8 kf0 = *(const bfrag8*)&Ks[buf][key * 64 + ((quad ^ sw) * 8)];
      bfrag8 kf1 = *(const bfrag8*)&Ks[buf][key * 64 + (((4 + quad) ^ sw) * 8)];
      sc[st] = __builtin_amdgcn_mfma_f32_16x16x32_bf16(kf0, qf[0], (f32x4)0.f, 0, 0, 0);
      sc[st] = __builtin_amdgcn_mfma_f32_16x16x32_bf16(kf1, qf[1], sc[st], 0, 0, 0);
    }
    __builtin_amdgcn_s_setprio(0);

    // ---- causal mask (diagonal-touching tiles; wave-uniform condition) ----
    if (j0 + 63 > qrow_base) {
      #pragma unroll
      for (int st = 0; st < 2; ++st)
        #pragma unroll
        for (int r = 0; r < 4; ++r) {
          int key = j0 + kh * 32 + st * 16 + quad * 4 + r;
          if (key > qrow_base + l15) sc[st][r] = -60.f;
        }
    }

    // ---- fixed-base softmax: p = exp2(s) (no clamp: |s|<<127, mask=-60) ----
    unsigned pk[2][2];
    float rs = 0.f;
    #pragma unroll
    for (int st = 0; st < 2; ++st) {
      float p0 = __builtin_amdgcn_exp2f(sc[st][0]);
      float p1 = __builtin_amdgcn_exp2f(sc[st][1]);
      float p2 = __builtin_amdgcn_exp2f(sc[st][2]);
      float p3 = __builtin_amdgcn_exp2f(sc[st][3]);
      rs += (p0 + p1) + (p2 + p3);
      pk[st][0] = pack_bf2(p0, p1);
      pk[st][1] = pack_bf2(p2, p3);
    }
    l_ += rs;

    // ---- in-register quad exchange: S^T C-layout -> PV B-fragment ----
    // (kc=0 slice of the R13-verified mapping; 8 bpermute + 4 cndmask)
    union PU { bfrag8 f; int i[4]; } u0;
    #pragma unroll
    for (int j = 0; j < 4; ++j) {
      const int adr = (j & 2) ? adr1 : adr0;
      int lo0 = __builtin_amdgcn_ds_bpermute(adr, (int)pk[0][j & 1]);
      int hi0 = __builtin_amdgcn_ds_bpermute(adr, (int)pk[1][j & 1]);
      u0.i[j] = (quad & 2) ? hi0 : lo0;
    }
    bfrag8 pf = u0.f;

    // ---- O^T += V^T·P (K=32: this wave's key half) ----
    __builtin_amdgcn_s_setprio(1);
    #pragma unroll
    for (int n0 = 0; n0 < 4; ++n0) {
      bfrag8 vf = *(const bfrag8*)&Vt[buf][(n0 * 16 + l15) * 64 + (((kh * 4 + quad) ^ sw) * 8)];
      oacc[n0] = __builtin_amdgcn_mfma_f32_16x16x32_bf16(vf, pf, oacc[n0], 0, 0, 0);
    }
    __builtin_amdgcn_s_setprio(0);
  }
  #undef STAGE

  // ---- epilogue: quad-reduce l; merge kh halves via LDS; store ----
  float l = l_;
  l += __shfl_xor(l, 16);
  l += __shfl_xor(l, 32);

  RAW_BARRIER();                           // all waves done reading K/V LDS
  float* osc = (float*)Ks;                 // 4 waves x 64 lanes x 16 f = 16KB
  float* lsc = (float*)Vt;                 // 4 x 16 f
  if (kh == 1) {
    #pragma unroll
    for (int n0 = 0; n0 < 4; ++n0)
      *(f32x4*)&osc[(wq * 64 + lane) * 16 + n0 * 4] = oacc[n0];
    if (quad == 0) lsc[wq * 16 + l15] = l;
  }
  RAW_BARRIER();
  if (kh == 0) {
    float lt = l + lsc[wq * 16 + l15];
    float inv = 1.f / lt;
    int q = qrow_base + l15;
    #pragma unroll
    for (int n0 = 0; n0 < 4; ++n0) {
      f32x4 o2 = *(const f32x4*)&osc[(wq * 64 + lane) * 16 + n0 * 4];
      u16x4 ov = { f2bf((oacc[n0][0] + o2[0]) * inv), f2bf((oacc[n0][1] + o2[1]) * inv),
                   f2bf((oacc[n0][2] + o2[2]) * inv), f2bf((oacc[n0][3] + o2[3]) * inv) };
      *(u16x4*)&obb[(size_t)(b * SEQ + q) * D_MODEL + h * DK + n0 * 16 + quad * 4] = ov;
    }
  }
}

// ---------------------------------------------------------------------------
extern "C" void kernel_launch(void* const* d_in, const int* in_sizes, int n_in,
                              void* d_out, int out_size, void* d_ws, size_t ws_size,
                              hipStream_t stream) {
  const float* x  = (const float*)d_in[0];
  const float* Wq = (const float*)d_in[1];
  const float* Wk = (const float*)d_in[2];
  const float* Wv = (const float*)d_in[3];
  const float* Wo = (const float*)d_in[4];
  const int* pos  = (const int*)d_in[5];

  const size_t XSZ = (size_t)MROWS * D_MODEL;   // 4M elems
  const size_t WSZ = (size_t)D_MODEL * D_MODEL; // 1M elems

  u16* bfb = (u16*)d_ws;
  u16* xb  = bfb;                     // 4M
  u16* wqb = xb  + XSZ;
  u16* wkb = wqb + WSZ;
  u16* wvb = wkb + WSZ;
  u16* wob = wvb + WSZ;
  u16* Qbf = wob + WSZ;               // 4M  [b,h,s,64]
  u16* Kbf = Qbf + XSZ;               // 4M  [b,h,s,64]
  u16* Vtb = Kbf + XSZ;               // 4M  [b,h,64,s]
  u16* obb = Vtb + XSZ;               // 4M  [b*s, h*64]
  float2* tab = (float2*)(obb + XSZ); // 131072 float2

  // 1. convert x + weights to bf16, and build RoPE table (fused)
  CvtPtrs cp; cp.src[0] = x; cp.src[1] = Wq; cp.src[2] = Wk; cp.src[3] = Wv; cp.src[4] = Wo;
  convert_and_tab<<<8192 + 512, 256, 0, stream>>>(cp, xb, pos, tab);

  // 2. QKV projections with fused RoPE/repack/V-transpose epilogue
  QKVArgs qp;
  qp.A[0] = wqb; qp.A[1] = wkb; qp.A[2] = xb;
  qp.B[0] = xb;  qp.B[1] = xb;  qp.B[2] = wvb;
  qp.dst[0] = Qbf; qp.dst[1] = Kbf; qp.dst[2] = Vtb;
  qp.tab = tab;
  gemm_qkv_fused<<<dim3(256, 1, 3), 256, 0, stream>>>(qp);

  // 3. flash attention: 1024 8-wave key-split blocks (32 waves/CU)
  attn_mfma<<<dim3(1024), 512, 0, stream>>>(Qbf, Kbf, Vtb, obb);

  // 4. output projection (128x64 tiles, 512 blocks)
  gemm_out_bf16<<<dim3(D_MODEL / 64, MROWS / 128), 256, 0, stream>>>(obb, wob, (float*)d_out);
}